// Round 10
// baseline (232.023 us; speedup 1.0000x reference)
//
#include <hip/hip_runtime.h>
#include <hip/hip_bf16.h>

#define D 64            // D_IN == D_OUT == 64
#define K 24            // slots/node; deg~Poisson(10): P(>24)~3e-5 -> ~10 spill edges (handled inline, exact)
#define M44 ((1ULL << 44) - 1)
#define SPILLCAP 65536

// ---------------------------------------------------------------------------
// k_build: SINGLE-PASS CSR (r8-proven). One packed 64-bit atomic/edge
// (count->rank in high 20 bits, fixed-point ew sum in low 44 -> exact deg) +
// one direct 4B record store slots[row*K+rank]. Record: (col<<15)|q15(ew).
// MEASURED WALLS: ~21.5G RMW/s device atomics (r5/r6: sharding flat ->
// throughput- not contention-bound); random slot store adds ~30us
// (WRITE_SIZE 61MB write-allocate). r10: 2 edges/thread -> two independent
// atomic->store chains to overlap store latency with the next atomic.
__global__ __launch_bounds__(256) void k_build(const int* __restrict__ rowi,
                                               const int* __restrict__ coli,
                                               const float* __restrict__ ew,
                                               unsigned long long* __restrict__ packed,
                                               unsigned int* __restrict__ slots,
                                               int4* __restrict__ spill,
                                               int* __restrict__ spillCnt,
                                               int nE, int half) {
    int e0 = blockIdx.x * 256 + threadIdx.x;
#pragma unroll
    for (int u = 0; u < 2; ++u) {
        int e = e0 + u * half;
        if (u == 0 ? (e0 < half) : (e < nE)) {
            int r = rowi[e];
            int c = coli[e];
            float w = ew[e];
            unsigned long long fx = (unsigned long long)((double)w * 4294967296.0);
            unsigned long long old = atomicAdd(&packed[r], (1ULL << 44) | fx);
            int rank = (int)(old >> 44);
            if (rank < K) {
                int q = (int)(w * 32768.0f + 0.5f);
                if (q > 32767) q = 32767;
                slots[r * K + rank] = ((unsigned int)c << 15) | (unsigned int)q;
            } else {
                int p = atomicAdd(spillCnt, 1);
                if (p < SPILLCAP) spill[p] = make_int4(r, c, __float_as_int(w), 0);
            }
        }
    }
}

// k_dis: dis[i]=rsqrt(1+sum_ew) exact from fixed point; cnt = RAW count
// (gather clamps to K and uses raw>K to trigger the inline spill scan).
__global__ __launch_bounds__(256) void k_dis(const unsigned long long* __restrict__ packed,
                                             float* __restrict__ dis,
                                             int* __restrict__ cnt, int n) {
    int i = blockIdx.x * 256 + threadIdx.x;
    if (i >= n) return;
    unsigned long long p = packed[i];
    float dg = (float)(1.0 + (double)(p & M44) * (1.0 / 4294967296.0));
    dis[i] = rsqrtf(dg);
    cnt[i] = (int)(p >> 44);
}

// k_gather: r5/r8-PROVEN SHAPE (one node per 16-lane group, max TLP -- r7
// lesson: never shrink a latency-bound gather's grid). fp32 x (r9: bf16 was
// measured NEUTRAL -> gather is latency/issue-bound, not line-count-bound).
// Lane j prefetches record off+j and its dis[col] (L2-resident 400KB),
// pre-multiplies weight, then 16 shuffle-broadcast independent x-row loads.
// Rare overflow nodes (raw cnt > K) scan the tiny spill list inline
// (broadcast reads, ~10 entries) -- replaces the k_spill dispatch.
// out_i = dis_i*(dis_i*x_i + sum w*dis_col*x[col]).  agg = d_out.
__global__ __launch_bounds__(256) void k_gather(const float* __restrict__ x,
                                                const float* __restrict__ dis,
                                                const int* __restrict__ cnt,
                                                const unsigned int* __restrict__ slots,
                                                const int4* __restrict__ spill,
                                                const int* __restrict__ spillCnt,
                                                float* __restrict__ agg, int n) {
    int g = blockIdx.x * 256 + threadIdx.x;
    int i = g >> 4;
    if (i >= n) return;
    int j = g & 15;

    const float4* x4 = (const float4*)x;
    float4 acc = make_float4(0.f, 0.f, 0.f, 0.f);
    int rawc = cnt[i];
    int c_n = rawc < K ? rawc : K;
    int s = i * K;
    for (int off = 0; off < c_n; off += 16) {
        int idx = off + j;
        unsigned int rec = 0u;
        float wj = 0.f;
        if (idx < c_n) {
            rec = slots[s + idx];
            wj = (float)(rec & 32767u) * (1.0f / 32768.0f) * dis[rec >> 15];
        }
        int mm = c_n - off; if (mm > 16) mm = 16;
#pragma unroll
        for (int t = 0; t < 16; ++t) {
            if (t < mm) {
                int col = (int)((unsigned int)__shfl((int)rec, t, 16) >> 15);
                float w = __shfl(wj, t, 16);
                float4 xv = x4[col * 16 + j];
                acc.x += w * xv.x; acc.y += w * xv.y;
                acc.z += w * xv.z; acc.w += w * xv.w;
            }
        }
    }
    if (rawc > K) {                      // statistically ~10 edges total
        int total = *spillCnt;
        if (total > SPILLCAP) total = SPILLCAP;
        for (int sp = 0; sp < total; ++sp) {
            int4 v = spill[sp];          // broadcast (same addr all lanes)
            if (v.x == i) {
                float w = __int_as_float(v.z) * dis[v.y];   // exact ew here
                float4 xv = x4[v.y * 16 + j];
                acc.x += w * xv.x; acc.y += w * xv.y;
                acc.z += w * xv.z; acc.w += w * xv.w;
            }
        }
    }
    float di = dis[i];
    float4 xi = x4[i * 16 + j];
    float4 o;
    o.x = di * (di * xi.x + acc.x);
    o.y = di * (di * xi.y + acc.y);
    o.z = di * (di * xi.z + acc.z);
    o.w = di * (di * xi.w + acc.w);
    ((float4*)agg)[i * 16 + j] = o;
}

// gcn_gemm: r5-PROVEN. Swizzled LDS (zero padding, bank floor), 4x4 register
// tile (16 outputs/thread amortizes LDS reads), launch_bounds(256,4) caps
// VGPR (r4 lesson: no shuffle lattices). In-place safe: block stages its 64
// rows to LDS before overwriting them.
__global__ __launch_bounds__(256, 4) void gcn_gemm(const float* __restrict__ agg,
                                                   const float* __restrict__ W,
                                                   const float* __restrict__ bias,
                                                   float* __restrict__ out, int n) {
    __shared__ float Ast[D * D];
    __shared__ float Bs[D * D];
    float4* Ast4 = (float4*)Ast;
    int tid = threadIdx.x;
    int r0 = blockIdx.x * 64;

    const float4* W4 = (const float4*)W;
    const float4* A4 = (const float4*)agg;
#pragma unroll
    for (int v = 0; v < 4; ++v) {
        int idx = tid + v * 256;
        int a  = idx >> 4;
        int kc = idx & 15;
        int ra = r0 + a;
        float4 av = make_float4(0.f, 0.f, 0.f, 0.f);
        if (ra < n) av = A4[ra * 16 + kc];
        Ast4[a * 16 + ((kc + (a >> 2)) & 15)] = av;
        float4 wv = W4[idx];
        int gq = a >> 2, oo = a & 3;
        { int k = 4 * kc + 0; Bs[k * 64 + 4 * ((gq + k) & 15) + oo] = wv.x; }
        { int k = 4 * kc + 1; Bs[k * 64 + 4 * ((gq + k) & 15) + oo] = wv.y; }
        { int k = 4 * kc + 2; Bs[k * 64 + 4 * ((gq + k) & 15) + oo] = wv.z; }
        { int k = 4 * kc + 3; Bs[k * 64 + 4 * ((gq + k) & 15) + oo] = wv.w; }
    }
    __syncthreads();

    int ty = tid >> 4;
    int tx = tid & 15;
    float acc[4][4];
#pragma unroll
    for (int m = 0; m < 4; ++m)
#pragma unroll
        for (int q = 0; q < 4; ++q) acc[m][q] = 0.f;

#pragma unroll 4
    for (int kc = 0; kc < 16; ++kc) {
        float4 a4[4], b4[4];
#pragma unroll
        for (int m = 0; m < 4; ++m)
            a4[m] = Ast4[(4 * ty + m) * 16 + ((kc + ty) & 15)];
#pragma unroll
        for (int i = 0; i < 4; ++i) {
            int k = 4 * kc + i;
            b4[i] = *(const float4*)&Bs[k * 64 + 4 * ((tx + k) & 15)];
        }
#pragma unroll
        for (int m = 0; m < 4; ++m) {
            acc[m][0] += a4[m].x * b4[0].x + a4[m].y * b4[1].x + a4[m].z * b4[2].x + a4[m].w * b4[3].x;
            acc[m][1] += a4[m].x * b4[0].y + a4[m].y * b4[1].y + a4[m].z * b4[2].y + a4[m].w * b4[3].y;
            acc[m][2] += a4[m].x * b4[0].z + a4[m].y * b4[1].z + a4[m].z * b4[2].z + a4[m].w * b4[3].z;
            acc[m][3] += a4[m].x * b4[0].w + a4[m].y * b4[1].w + a4[m].z * b4[2].w + a4[m].w * b4[3].w;
        }
    }

    float4 bv = ((const float4*)bias)[tx];
    float4* out4 = (float4*)out;
#pragma unroll
    for (int m = 0; m < 4; ++m) {
        int r = r0 + 4 * ty + m;
        if (r < n) {
            float4 o;
            o.x = acc[m][0] + bv.x; o.y = acc[m][1] + bv.y;
            o.z = acc[m][2] + bv.z; o.w = acc[m][3] + bv.w;
            out4[r * 16 + tx] = o;
        }
    }
}

extern "C" void kernel_launch(void* const* d_in, const int* in_sizes, int n_in,
                              void* d_out, int out_size, void* d_ws, size_t ws_size,
                              hipStream_t stream) {
    const float* x    = (const float*)d_in[0];
    const int*   ei   = (const int*)d_in[1];   // [2*E] flat: rows then cols
    const float* ew   = (const float*)d_in[2];
    const float* W    = (const float*)d_in[3];
    const float* bias = (const float*)d_in[4];
    float* out = (float*)d_out;

    int n  = in_sizes[0] / D;   // 100000
    int nE = in_sizes[2];       // 1000000
    const int* rowi = ei;
    const int* coli = ei + nE;

    // workspace (~12.3 MB): packed | spillCnt | slots | dis | cnt | spill
    char* w = (char*)d_ws;
    unsigned long long* packed = (unsigned long long*)w; w += (size_t)n * 8;
    int* spillCnt = (int*)w;                             w += 64;
    unsigned int* slots = (unsigned int*)w;              w += (size_t)n * K * 4;
    float* dis = (float*)w;                              w += (size_t)n * 4;
    int*   cnt = (int*)w;                                w += (size_t)n * 4;
    int4*  spill = (int4*)w;

    int gn   = (n + 255) / 256;
    int gNd  = (n * 16 + 255) / 256;
    int half = (nE + 1) / 2;
    int gE2  = (half + 255) / 256;

    hipMemsetAsync(packed, 0, (size_t)n * 8 + 64, stream);   // packed + spillCnt
    k_build <<<gE2, 256, 0, stream>>>(rowi, coli, ew, packed, slots, spill, spillCnt, nE, half);
    k_dis   <<<gn, 256, 0, stream>>>(packed, dis, cnt, n);
    k_gather<<<gNd, 256, 0, stream>>>(x, dis, cnt, slots, spill, spillCnt, out, n);
    gcn_gemm<<<(n + 63) / 64, 256, 0, stream>>>(out, W, bias, out, n);
}

// Round 11
// 213.266 us; speedup vs baseline: 1.0880x; 1.0880x over previous
//
#include <hip/hip_runtime.h>
#include <hip/hip_bf16.h>

#define D 64            // D_IN == D_OUT == 64
#define K 24            // slots/node; deg~Poisson(10): P(>24)~3e-5 -> ~10 spill edges (inline, exact)
#define M44 ((1ULL << 44) - 1)
#define SPILLCAP 65536

// ---------------------------------------------------------------------------
// k_build: SINGLE-PASS CSR (r8-proven 78us shape — 1 edge/thread, max TLP;
// r10 measured: 2 edges/thread regresses to 89us, the atomic pipe wants one
// independent chain per thread). One packed 64-bit atomic/edge (count->rank
// high 20 bits, fixed-point ew sum low 44 -> exact deg) + one direct 4B
// record store slots[row*K+rank]. Record: (col<<15)|q15(ew).
// MEASURED WALL: ~21.5G RMW/s device atomics (r5/r6 sharding flat).
__global__ __launch_bounds__(256) void k_build(const int* __restrict__ rowi,
                                               const int* __restrict__ coli,
                                               const float* __restrict__ ew,
                                               unsigned long long* __restrict__ packed,
                                               unsigned int* __restrict__ slots,
                                               int4* __restrict__ spill,
                                               int* __restrict__ spillCnt, int nE) {
    int e = blockIdx.x * 256 + threadIdx.x;
    if (e >= nE) return;
    int r = rowi[e];
    int c = coli[e];
    float w = ew[e];
    unsigned long long fx = (unsigned long long)((double)w * 4294967296.0);
    unsigned long long old = atomicAdd(&packed[r], (1ULL << 44) | fx);
    int rank = (int)(old >> 44);
    if (rank < K) {
        int q = (int)(w * 32768.0f + 0.5f);
        if (q > 32767) q = 32767;
        slots[r * K + rank] = ((unsigned int)c << 15) | (unsigned int)q;
    } else {
        int p = atomicAdd(spillCnt, 1);
        if (p < SPILLCAP) spill[p] = make_int4(r, c, __float_as_int(w), 0);
    }
}

// k_dis: dis[i]=rsqrt(1+sum_ew) exact from fixed point; cnt = RAW count
// (gather clamps to K; raw>K triggers the inline spill scan).
__global__ __launch_bounds__(256) void k_dis(const unsigned long long* __restrict__ packed,
                                             float* __restrict__ dis,
                                             int* __restrict__ cnt, int n) {
    int i = blockIdx.x * 256 + threadIdx.x;
    if (i >= n) return;
    unsigned long long p = packed[i];
    float dg = (float)(1.0 + (double)(p & M44) * (1.0 / 4294967296.0));
    dis[i] = rsqrtf(dg);
    cnt[i] = (int)(p >> 44);
}

// k_gather_gemm: FUSED, grid NOT shrunk (r7 lesson — 6250 blocks, 1 node per
// 16-lane group = identical gather TLP to the standalone r8 gather).
//  Phase 0: stage W (transposed+swizzled, r5-proven layout) — before the
//           gather so the LDS stores overlap gather latency.
//  Phase 1: group grp gathers node i = blk*16+grp:
//           agg_i = dis_i*(dis_i*x_i + sum w*dis_col*x[col]); rare overflow
//           (raw cnt>K) scans the tiny spill list inline (broadcast reads).
//           Result float4 -> swizzled 16-row Ast LDS tile (no HBM agg trip).
//  Phase 2: 16x64 mini-GEMM: thread (row=tid>>4, cg=tid&15) computes
//           out[i0+row][4cg..4cg+3], 256 FMA/thread, LDS reads at bank floor
//           (Ast: same-addr broadcast across cg; Bs: r5 swizzle).
__global__ __launch_bounds__(256) void k_gather_gemm(const float* __restrict__ x,
                                                     const float* __restrict__ dis,
                                                     const int* __restrict__ cnt,
                                                     const unsigned int* __restrict__ slots,
                                                     const int4* __restrict__ spill,
                                                     const int* __restrict__ spillCnt,
                                                     const float* __restrict__ W,
                                                     const float* __restrict__ bias,
                                                     float* __restrict__ out, int n) {
    __shared__ float Bs[D * D];        // 16 KB: Bs[k][o] = W[o][k], swizzled
    __shared__ float Ast[16 * D];      // 4 KB: 16-row A tile, swizzled float4 slots
    float4* Ast4 = (float4*)Ast;
    int tid = threadIdx.x;

    // Phase 0: stage W (issue first; overlaps the gather's global loads)
    const float4* W4 = (const float4*)W;
#pragma unroll
    for (int v = 0; v < 4; ++v) {
        int idx = tid + v * 256;       // 0..1023
        int o  = idx >> 4;             // out-ch 0..63
        int kc = idx & 15;
        float4 wv = W4[idx];
        int gq = o >> 2, oo = o & 3;
        { int k = 4 * kc + 0; Bs[k * 64 + 4 * ((gq + k) & 15) + oo] = wv.x; }
        { int k = 4 * kc + 1; Bs[k * 64 + 4 * ((gq + k) & 15) + oo] = wv.y; }
        { int k = 4 * kc + 2; Bs[k * 64 + 4 * ((gq + k) & 15) + oo] = wv.z; }
        { int k = 4 * kc + 3; Bs[k * 64 + 4 * ((gq + k) & 15) + oo] = wv.w; }
    }

    // Phase 1: gather (one node per 16-lane group)
    int j   = tid & 15;                // k-chunk lane
    int grp = tid >> 4;                // 0..15
    int i0  = blockIdx.x * 16;
    int i   = i0 + grp;

    float4 acc = make_float4(0.f, 0.f, 0.f, 0.f);
    const float4* x4 = (const float4*)x;
    if (i < n) {
        int rawc = cnt[i];
        int c_n = rawc < K ? rawc : K;
        int s = i * K;
        for (int off = 0; off < c_n; off += 16) {
            int idx = off + j;
            unsigned int rec = 0u;
            float wj = 0.f;
            if (idx < c_n) {
                rec = slots[s + idx];
                wj = (float)(rec & 32767u) * (1.0f / 32768.0f) * dis[rec >> 15];
            }
            int mm = c_n - off; if (mm > 16) mm = 16;
#pragma unroll
            for (int t = 0; t < 16; ++t) {
                if (t < mm) {
                    int col = (int)((unsigned int)__shfl((int)rec, t, 16) >> 15);
                    float w = __shfl(wj, t, 16);
                    float4 xv = x4[col * 16 + j];
                    acc.x += w * xv.x; acc.y += w * xv.y;
                    acc.z += w * xv.z; acc.w += w * xv.w;
                }
            }
        }
        if (rawc > K) {                // ~10 edges total in the whole graph
            int total = *spillCnt;
            if (total > SPILLCAP) total = SPILLCAP;
            for (int sp = 0; sp < total; ++sp) {
                int4 v = spill[sp];    // broadcast
                if (v.x == i) {
                    float w = __int_as_float(v.z) * dis[v.y];
                    float4 xv = x4[v.y * 16 + j];
                    acc.x += w * xv.x; acc.y += w * xv.y;
                    acc.z += w * xv.z; acc.w += w * xv.w;
                }
            }
        }
        float di = dis[i];
        float4 xi = x4[i * 16 + j];
        acc.x = di * (di * xi.x + acc.x);
        acc.y = di * (di * xi.y + acc.y);
        acc.z = di * (di * xi.z + acc.z);
        acc.w = di * (di * xi.w + acc.w);
    }
    Ast4[grp * 16 + ((j + (grp >> 2)) & 15)] = acc;   // swizzled slot
    __syncthreads();

    // Phase 2: 16x64 mini-GEMM
    int row = tid >> 4;                // 0..15 (tile row)
    int cg  = tid & 15;                // out-ch group: 4cg..4cg+3
    float4 oacc = ((const float4*)bias)[cg];
#pragma unroll 4
    for (int kc = 0; kc < 16; ++kc) {
        float4 a4 = Ast4[row * 16 + ((kc + (row >> 2)) & 15)];
        float4 b0 = *(const float4*)&Bs[(4 * kc + 0) * 64 + 4 * ((cg + 4 * kc + 0) & 15)];
        float4 b1 = *(const float4*)&Bs[(4 * kc + 1) * 64 + 4 * ((cg + 4 * kc + 1) & 15)];
        float4 b2 = *(const float4*)&Bs[(4 * kc + 2) * 64 + 4 * ((cg + 4 * kc + 2) & 15)];
        float4 b3 = *(const float4*)&Bs[(4 * kc + 3) * 64 + 4 * ((cg + 4 * kc + 3) & 15)];
        oacc.x += a4.x * b0.x + a4.y * b1.x + a4.z * b2.x + a4.w * b3.x;
        oacc.y += a4.x * b0.y + a4.y * b1.y + a4.z * b2.y + a4.w * b3.y;
        oacc.z += a4.x * b0.z + a4.y * b1.z + a4.z * b2.z + a4.w * b3.z;
        oacc.w += a4.x * b0.w + a4.y * b1.w + a4.z * b2.w + a4.w * b3.w;
    }
    int r = i0 + row;
    if (r < n) ((float4*)out)[r * 16 + cg] = oacc;
}

extern "C" void kernel_launch(void* const* d_in, const int* in_sizes, int n_in,
                              void* d_out, int out_size, void* d_ws, size_t ws_size,
                              hipStream_t stream) {
    const float* x    = (const float*)d_in[0];
    const int*   ei   = (const int*)d_in[1];   // [2*E] flat: rows then cols
    const float* ew   = (const float*)d_in[2];
    const float* W    = (const float*)d_in[3];
    const float* bias = (const float*)d_in[4];
    float* out = (float*)d_out;

    int n  = in_sizes[0] / D;   // 100000
    int nE = in_sizes[2];       // 1000000
    const int* rowi = ei;
    const int* coli = ei + nE;

    // workspace (~12.2 MB): packed | spillCnt | slots | dis | cnt | spill
    char* w = (char*)d_ws;
    unsigned long long* packed = (unsigned long long*)w; w += (size_t)n * 8;
    int* spillCnt = (int*)w;                             w += 64;
    unsigned int* slots = (unsigned int*)w;              w += (size_t)n * K * 4;
    float* dis = (float*)w;                              w += (size_t)n * 4;
    int*   cnt = (int*)w;                                w += (size_t)n * 4;
    int4*  spill = (int4*)w;

    int gn = (n + 255) / 256;
    int gE = (nE + 255) / 256;
    int gT = (n + 15) / 16;     // 6250 blocks: 16 nodes/block, 1 node/group

    hipMemsetAsync(packed, 0, (size_t)n * 8 + 64, stream);   // packed + spillCnt
    k_build<<<gE, 256, 0, stream>>>(rowi, coli, ew, packed, slots, spill, spillCnt, nE);
    k_dis  <<<gn, 256, 0, stream>>>(packed, dis, cnt, n);
    k_gather_gemm<<<gT, 256, 0, stream>>>(x, dis, cnt, slots, spill, spillCnt, W, bias, out, n);
}